// Round 9
// baseline (407.009 us; speedup 1.0000x reference)
//
#include <hip/hip_runtime.h>

#define NB 4
#define NN 200000
#define HH 512
#define WW 512
#define CC 64
#define PP 150000
#define RP 100000
#define HWSZ (HH * WW)
#define NPTS (NB * NN)
#define NTILES (NPTS / 16)                 // 50000 (exact)
#define XSHIFT 4                           // 16 floats = one 64B line along x
#define BINS_PER_B (HH * (WW >> XSHIFT))   // 16384
#define NBINS (NB * BINS_PER_B)            // 65536

// wbuf layout (32-bit words):
#define WB_WCAT 0
#define WB_WTAIL 5120
#define WB_BCAT 5312
#define WB_BFRAG 5376
#define WB_BFRAG2 (WB_BFRAG + 3072)
#define WBUF_WORDS (WB_BFRAG2 + 256)       // 8704

typedef _Float16 half8_t __attribute__((ext_vector_type(8)));
typedef _Float16 half2_t __attribute__((ext_vector_type(2)));
typedef float f32x4 __attribute__((ext_vector_type(4)));

__device__ __forceinline__ unsigned packh(float a, float b) {
    half2_t h; h.x = (_Float16)a; h.y = (_Float16)b;
    unsigned u; __builtin_memcpy(&u, &h, 4); return u;
}
__device__ __forceinline__ float gelu(float v) {
    return 0.5f * v * (1.0f + erff(v * 0.70710678118654752f));
}
__device__ __forceinline__ int bin_of(int b, int y, int x) {
    return b * BINS_PER_B + y * (WW >> XSHIFT) + (x >> XSHIFT);
}

// ---------------- prep: zero bins (blocks 0..255) + build weights (block 256) ----

__device__ __forceinline__ float wrowf(const float* __restrict__ wbuf, int k, int col) {
    if (k < 160) return wbuf[WB_WCAT + k * 32 + col];
    if (k < 166) return wbuf[WB_WTAIL + (k - 160) * 32 + col];
    if (k == 166) return wbuf[WB_BCAT + col];
    return 0.f;
}

__global__ __launch_bounds__(256) void prep_kernel(
    const float* __restrict__ Wf, const float* __restrict__ bf,
    const float* __restrict__ Wp, const float* __restrict__ bp,
    const float* __restrict__ W1, const float* __restrict__ b1,
    const float* __restrict__ W2,
    float* __restrict__ wbuf, unsigned* __restrict__ cnt)
{
    if (blockIdx.x < 256) {                      // zero 65536 bins
        cnt[blockIdx.x * 256 + threadIdx.x] = 0u;
        return;
    }
    float* Wcat = wbuf + WB_WCAT;
    float* Wtail = wbuf + WB_WTAIL;
    float* bcat = wbuf + WB_BCAT;
    int t = threadIdx.x;
    for (int idx = t; idx < 160 * 32; idx += 256) {
        int r = idx >> 5, j = idx & 31;
        float s = 0.f;
        if (r < 64) {
            for (int k = 0; k < 32; ++k) s += Wf[r * 32 + k] * W1[k * 32 + j];
        } else {
            int rr = r - 64;
            for (int k = 0; k < 32; ++k) s += Wp[rr * 32 + k] * W1[(32 + k) * 32 + j];
        }
        Wcat[idx] = s;
    }
    for (int idx = t; idx < 6 * 32; idx += 256) {
        int r = idx >> 5, j = idx & 31;
        float s = 0.f;
        for (int k = 0; k < 32; ++k) s += Wf[(64 + r) * 32 + k] * W1[k * 32 + j];
        Wtail[idx] = s;
    }
    for (int j = t; j < 32; j += 256) {
        float s = b1[j];
        for (int k = 0; k < 32; ++k)
            s += bf[k] * W1[k * 32 + j] + bp[k] * W1[(32 + k) * 32 + j];
        bcat[j] = s;
    }
    __syncthreads();
    unsigned* BF = (unsigned*)(wbuf + WB_BFRAG);
    for (int idx = t; idx < 2 * 6 * 64 * 4; idx += 256) {
        int w = idx & 3;
        int slot = idx >> 2;
        int l = slot & 63;
        int rest = slot >> 6;
        int tt = rest % 6, nt = rest / 6;
        int k = tt * 32 + (l >> 4) * 8 + w * 2;
        int col = nt * 16 + (l & 15);
        BF[idx] = packh(wrowf(wbuf, k, col), wrowf(wbuf, k + 1, col));
    }
    for (int idx = t; idx < 64 * 4; idx += 256) {
        int w = idx & 3, l = idx >> 2;
        int k2 = (l >> 4) * 8 + w * 2, col = l & 15;
        BF[3072 + idx] = packh(W2[k2 * 16 + col], W2[(k2 + 1) * 16 + col]);
    }
}

// ---------------- hist (also caches packed yx) ----------------

__global__ __launch_bounds__(256) void hist_kernel(
    const int* __restrict__ voxel, unsigned* __restrict__ cnt,
    unsigned* __restrict__ yxp) {
    int pid = blockIdx.x * 256 + threadIdx.x;
    if (pid >= NPTS) return;
    int b = pid / NN;
    int y = voxel[(size_t)pid * 3 + 1];
    int x = voxel[(size_t)pid * 3 + 2];
    yxp[pid] = ((unsigned)y << 16) | (unsigned)x;
    atomicAdd(&cnt[bin_of(b, y, x)], 1u);
}

// ---------------- scan (single block, uint4-vectorized) ----------------

__global__ __launch_bounds__(1024) void scan_kernel(
    const unsigned* __restrict__ cnt, unsigned* __restrict__ off) {
    __shared__ unsigned lds[1024];
    int t = threadIdx.x;
    const uint4* c4 = (const uint4*)cnt;
    unsigned sum = 0;
    #pragma unroll 4
    for (int i = 0; i < 16; ++i) {
        uint4 c = c4[t * 16 + i];
        sum += c.x + c.y + c.z + c.w;
    }
    lds[t] = sum;
    __syncthreads();
    for (int d = 1; d < 1024; d <<= 1) {
        unsigned v = (t >= d) ? lds[t - d] : 0u;
        __syncthreads();
        lds[t] += v;
        __syncthreads();
    }
    unsigned run = (t == 0) ? 0u : lds[t - 1];
    uint4* o4 = (uint4*)off;
    #pragma unroll 4
    for (int i = 0; i < 16; ++i) {
        uint4 c = c4[t * 16 + i];
        uint4 o;
        o.x = run;
        o.y = o.x + c.x;
        o.z = o.y + c.y;
        o.w = o.z + c.z;
        run = o.w + c.w;
        o4[t * 16 + i] = o;
    }
}

// ---------------- scatter: write fused {pid, yx} ----------------

__global__ __launch_bounds__(256) void scatter_kernel(
    const unsigned* __restrict__ yxp, unsigned* __restrict__ off,
    uint2* __restrict__ oy) {
    int pid = blockIdx.x * 256 + threadIdx.x;
    if (pid >= NPTS) return;
    unsigned p = yxp[pid];
    int y = (int)(p >> 16), x = (int)(p & 0xffffu);
    unsigned pos = atomicAdd(&off[bin_of(pid / NN, y, x)], 1u);
    uint2 q; q.x = (unsigned)pid; q.y = p;
    oy[pos] = q;
}

// ---------------- fused gather + MFMA MLP (1 tile/wave, nt loads) ----------------

__global__ __launch_bounds__(512, 8) void mlp_fused(
    const float* __restrict__ pc0_map, const float* __restrict__ flow_map,
    const float* __restrict__ pc0_fea, const float* __restrict__ flows,
    const float* __restrict__ pose_flows, const float* __restrict__ radar_pose,
    const int* __restrict__ point_idxes,
    const uint2* __restrict__ oy,
    const float* __restrict__ wbuf,
    const float* __restrict__ b2, const float* __restrict__ W3,
    const float* __restrict__ b3,
    float* __restrict__ out)
{
    __shared__ uint4 Bf[832];
    __shared__ __align__(16) _Float16 zl[8][16 * 48];
    {
        const uint4* wsrc = (const uint4*)(wbuf + WB_BFRAG);
        for (int i = threadIdx.x; i < 832; i += 512) Bf[i] = wsrc[i];
    }
    __syncthreads();

    int wave = threadIdx.x >> 6;
    int l = threadIdx.x & 63;
    int lo = l & 15, hi = l >> 4;
    int tile = blockIdx.x * 8 + wave;        // grid sized exactly
    int s0 = tile * 16;

    uint2 q = oy[s0 + lo];
    int pid = (int)q.x;
    int y = (int)(q.y >> 16), x = (int)(q.y & 0xffffu);
    int b = pid / NN;

    const float* fm = flow_map + ((size_t)b * CC) * HWSZ + (size_t)y * WW + x;
    const float* pm = pc0_map  + ((size_t)b * CC) * HWSZ + (size_t)y * WW + x;

    // issue all scattered loads (nt: no L1 reuse exists for these)
    float v[32];
    #pragma unroll
    for (int t = 0; t < 4; ++t) {
        const float* mp = (t < 2) ? fm : pm;
        int ch0 = (t & 1) * 32 + hi * 8;
        #pragma unroll
        for (int j = 0; j < 8; ++j)
            v[t * 8 + j] = __builtin_nontemporal_load(&mp[(size_t)(ch0 + j) * HWSZ]);
    }
    const f32x4* fe4 = (const f32x4*)(pc0_fea + (size_t)pid * 32 + hi * 8);
    f32x4 fa = __builtin_nontemporal_load(fe4);
    f32x4 fb = __builtin_nontemporal_load(fe4 + 1);
    float t0 = 0.f, t1 = 0.f, t2 = 0.f, t3 = 0.f, t4 = 0.f, t5 = 0.f;
    if (hi == 0) {
        const float* fl = flows + (size_t)pid * 3;
        t0 = __builtin_nontemporal_load(&fl[0]);
        t1 = __builtin_nontemporal_load(&fl[1]);
        t2 = __builtin_nontemporal_load(&fl[2]);
        int pi = point_idxes[pid];
        const float* ps = (pi < PP) ? (pose_flows + ((size_t)b * PP + pi) * 3)
                                    : (radar_pose + ((size_t)b * RP + (pi - PP)) * 3);
        t3 = ps[0]; t4 = ps[1]; t5 = ps[2];
    }

    // build A fragments
    half8_t A[6];
    #pragma unroll
    for (int t = 0; t < 4; ++t) {
        #pragma unroll
        for (int j = 0; j < 8; ++j) A[t][j] = (_Float16)v[t * 8 + j];
    }
    A[4][0] = (_Float16)fa.x; A[4][1] = (_Float16)fa.y;
    A[4][2] = (_Float16)fa.z; A[4][3] = (_Float16)fa.w;
    A[4][4] = (_Float16)fb.x; A[4][5] = (_Float16)fb.y;
    A[4][6] = (_Float16)fb.z; A[4][7] = (_Float16)fb.w;
    {
        half8_t a5;
        #pragma unroll
        for (int j = 0; j < 8; ++j) a5[j] = (_Float16)0.f;
        if (hi == 0) {
            a5[0] = (_Float16)t0; a5[1] = (_Float16)t1; a5[2] = (_Float16)t2;
            a5[3] = (_Float16)t3; a5[4] = (_Float16)t4; a5[5] = (_Float16)t5;
            a5[6] = (_Float16)1.0f;
        }
        A[5] = a5;
    }

    // layer1 (collapsed): z[16 pts][32 ch]
    f32x4 acc0 = {0.f, 0.f, 0.f, 0.f};
    f32x4 acc1 = {0.f, 0.f, 0.f, 0.f};
    #pragma unroll
    for (int t = 0; t < 6; ++t) {
        half8_t B0, B1;
        uint4 u0 = Bf[t * 64 + l];
        uint4 u1 = Bf[(6 + t) * 64 + l];
        __builtin_memcpy(&B0, &u0, 16);
        __builtin_memcpy(&B1, &u1, 16);
        acc0 = __builtin_amdgcn_mfma_f32_16x16x32_f16(A[t], B0, acc0, 0, 0, 0);
        acc1 = __builtin_amdgcn_mfma_f32_16x16x32_f16(A[t], B1, acc1, 0, 0, 0);
    }

    // gelu -> z LDS (f16), C-layout: point = hi*4+r, ch = nt*16+lo
    _Float16* zw = zl[wave];
    #pragma unroll
    for (int r = 0; r < 4; ++r) {
        zw[(hi * 4 + r) * 48 + lo]      = (_Float16)gelu(acc0[r]);
        zw[(hi * 4 + r) * 48 + 16 + lo] = (_Float16)gelu(acc1[r]);
    }

    // layer2
    half8_t A2, B2;
    __builtin_memcpy(&A2, &zw[lo * 48 + hi * 8], 16);
    {
        uint4 u2 = Bf[768 + l];
        __builtin_memcpy(&B2, &u2, 16);
    }
    f32x4 zz4 = {0.f, 0.f, 0.f, 0.f};
    f32x4 acc2 = __builtin_amdgcn_mfma_f32_16x16x32_f16(A2, B2, zz4, 0, 0, 0);

    // epilogue
    float b2v = b2[lo];
    float w3v = W3[lo];
    float e0 = gelu(acc2[0] + b2v) * w3v;
    float e1 = gelu(acc2[1] + b2v) * w3v;
    float e2 = gelu(acc2[2] + b2v) * w3v;
    float e3 = gelu(acc2[3] + b2v) * w3v;
    #pragma unroll
    for (int m = 1; m <= 8; m <<= 1) {
        e0 += __shfl_xor(e0, m);
        e1 += __shfl_xor(e1, m);
        e2 += __shfl_xor(e2, m);
        e3 += __shfl_xor(e3, m);
    }
    int p2 = hi * 4 + lo;
    int pid2 = __shfl(pid, p2 & 15);
    if (lo < 4) {
        float zs = (lo == 0 ? e0 : lo == 1 ? e1 : lo == 2 ? e2 : e3) + b3[0];
        float score = 1.0f / (1.0f + expf(-zs));
        out[(size_t)NPTS + pid2] = score;
        out[pid2] = (score > 0.5f) ? 1.0f : 0.0f;
    }
}

extern "C" void kernel_launch(void* const* d_in, const int* in_sizes, int n_in,
                              void* d_out, int out_size, void* d_ws, size_t ws_size,
                              hipStream_t stream) {
    const float* pc0_map    = (const float*)d_in[0];
    const float* flow_map   = (const float*)d_in[1];
    const float* pc0_fea    = (const float*)d_in[2];
    const float* flows      = (const float*)d_in[3];
    const float* pose_flows = (const float*)d_in[4];
    const float* radar_pose = (const float*)d_in[5];
    const int*   voxel      = (const int*)d_in[6];
    const int*   pidx       = (const int*)d_in[7];
    const float* W_flow = (const float*)d_in[8];
    const float* b_flow = (const float*)d_in[9];
    const float* W_pc   = (const float*)d_in[10];
    const float* b_pc   = (const float*)d_in[11];
    const float* W1     = (const float*)d_in[12];
    const float* b1     = (const float*)d_in[13];
    const float* W2     = (const float*)d_in[14];
    const float* b2     = (const float*)d_in[15];
    const float* W3     = (const float*)d_in[16];
    const float* b3     = (const float*)d_in[17];

    // ws: cnt[NBINS] | off[NBINS] | oy[NPTS] (uint2) | yxp[NPTS] | wbuf
    size_t need = (size_t)(2 * NBINS + 3 * NPTS) * sizeof(unsigned)
                + (size_t)WBUF_WORDS * sizeof(float);
    if (ws_size < need) return;
    unsigned* cnt = (unsigned*)d_ws;
    unsigned* off = cnt + NBINS;
    uint2* oy = (uint2*)(off + NBINS);
    unsigned* yxp = (unsigned*)(oy + NPTS);
    float* wbuf = (float*)(yxp + NPTS);

    int ptBlocks = NPTS / 256;               // 3125 exact

    hipLaunchKernelGGL(prep_kernel, dim3(257), dim3(256), 0, stream,
                       W_flow, b_flow, W_pc, b_pc, W1, b1, W2, wbuf, cnt);
    hipLaunchKernelGGL(hist_kernel, dim3(ptBlocks), dim3(256), 0, stream,
                       voxel, cnt, yxp);
    hipLaunchKernelGGL(scan_kernel, dim3(1), dim3(1024), 0, stream, cnt, off);
    hipLaunchKernelGGL(scatter_kernel, dim3(ptBlocks), dim3(256), 0, stream,
                       yxp, off, oy);
    hipLaunchKernelGGL(mlp_fused, dim3(NTILES / 8), dim3(512), 0, stream,
                       pc0_map, flow_map, pc0_fea, flows, pose_flows, radar_pose,
                       pidx, oy, wbuf, b2, W3, b3, (float*)d_out);
}

// Round 10
// 345.211 us; speedup vs baseline: 1.1790x; 1.1790x over previous
//
#include <hip/hip_runtime.h>

#define NB 4
#define NN 200000
#define HH 512
#define WW 512
#define CC 64
#define PP 150000
#define RP 100000
#define HWSZ (HH * WW)
#define NPTS (NB * NN)
#define NTILES (NPTS / 16)                 // 50000 (exact)
#define XSHIFT 4                           // 16 floats = one 64B line along x
#define BINS_PER_B (HH * (WW >> XSHIFT))   // 16384
#define NBINS (NB * BINS_PER_B)            // 65536

// wbuf layout (32-bit words):
#define WB_WCAT 0
#define WB_WTAIL 5120
#define WB_BCAT 5312
#define WB_BFRAG 5376
#define WB_BFRAG2 (WB_BFRAG + 3072)
#define WBUF_WORDS (WB_BFRAG2 + 256)       // 8704

typedef _Float16 half8_t __attribute__((ext_vector_type(8)));
typedef _Float16 half2_t __attribute__((ext_vector_type(2)));
typedef float f32x4 __attribute__((ext_vector_type(4)));

__device__ __forceinline__ unsigned packh(float a, float b) {
    half2_t h; h.x = (_Float16)a; h.y = (_Float16)b;
    unsigned u; __builtin_memcpy(&u, &h, 4); return u;
}
__device__ __forceinline__ float gelu(float v) {
    return 0.5f * v * (1.0f + erff(v * 0.70710678118654752f));
}
__device__ __forceinline__ int bin_of(int b, int y, int x) {
    return b * BINS_PER_B + y * (WW >> XSHIFT) + (x >> XSHIFT);
}

__device__ __forceinline__ float wrowf(const float* __restrict__ wbuf, int k, int col) {
    if (k < 160) return wbuf[WB_WCAT + k * 32 + col];
    if (k < 166) return wbuf[WB_WTAIL + (k - 160) * 32 + col];
    if (k == 166) return wbuf[WB_BCAT + col];
    return 0.f;
}

// ---------------- hist (+ yx cache) with weight build folded into block 0 ----

__global__ __launch_bounds__(256) void hist_prep(
    const int* __restrict__ voxel, unsigned* __restrict__ cnt,
    unsigned* __restrict__ yxp,
    const float* __restrict__ Wf, const float* __restrict__ bf,
    const float* __restrict__ Wp, const float* __restrict__ bp,
    const float* __restrict__ W1, const float* __restrict__ b1,
    const float* __restrict__ W2,
    float* __restrict__ wbuf)
{
    int pid = blockIdx.x * 256 + threadIdx.x;
    if (pid < NPTS) {
        int b = pid / NN;
        int y = voxel[(size_t)pid * 3 + 1];
        int x = voxel[(size_t)pid * 3 + 2];
        yxp[pid] = ((unsigned)y << 16) | (unsigned)x;
        atomicAdd(&cnt[bin_of(b, y, x)], 1u);
    }
    if (blockIdx.x != 0) return;

    // block 0: collapsed-weight build (runs in parallel with other blocks' hist)
    float* Wcat = wbuf + WB_WCAT;
    float* Wtail = wbuf + WB_WTAIL;
    float* bcat = wbuf + WB_BCAT;
    int t = threadIdx.x;
    for (int idx = t; idx < 160 * 32; idx += 256) {
        int r = idx >> 5, j = idx & 31;
        float s = 0.f;
        if (r < 64) {
            for (int k = 0; k < 32; ++k) s += Wf[r * 32 + k] * W1[k * 32 + j];
        } else {
            int rr = r - 64;
            for (int k = 0; k < 32; ++k) s += Wp[rr * 32 + k] * W1[(32 + k) * 32 + j];
        }
        Wcat[idx] = s;
    }
    for (int idx = t; idx < 6 * 32; idx += 256) {
        int r = idx >> 5, j = idx & 31;
        float s = 0.f;
        for (int k = 0; k < 32; ++k) s += Wf[(64 + r) * 32 + k] * W1[k * 32 + j];
        Wtail[idx] = s;
    }
    for (int j = t; j < 32; j += 256) {
        float s = b1[j];
        for (int k = 0; k < 32; ++k)
            s += bf[k] * W1[k * 32 + j] + bp[k] * W1[(32 + k) * 32 + j];
        bcat[j] = s;
    }
    __syncthreads();
    unsigned* BF = (unsigned*)(wbuf + WB_BFRAG);
    for (int idx = t; idx < 2 * 6 * 64 * 4; idx += 256) {
        int w = idx & 3;
        int slot = idx >> 2;
        int l = slot & 63;
        int rest = slot >> 6;
        int tt = rest % 6, nt = rest / 6;
        int k = tt * 32 + (l >> 4) * 8 + w * 2;
        int col = nt * 16 + (l & 15);
        BF[idx] = packh(wrowf(wbuf, k, col), wrowf(wbuf, k + 1, col));
    }
    for (int idx = t; idx < 64 * 4; idx += 256) {
        int w = idx & 3, l = idx >> 2;
        int k2 = (l >> 4) * 8 + w * 2, col = l & 15;
        BF[3072 + idx] = packh(W2[k2 * 16 + col], W2[(k2 + 1) * 16 + col]);
    }
}

// ---------------- scan (single block, uint4-vectorized) ----------------

__global__ __launch_bounds__(1024) void scan_kernel(
    const unsigned* __restrict__ cnt, unsigned* __restrict__ off) {
    __shared__ unsigned lds[1024];
    int t = threadIdx.x;
    const uint4* c4 = (const uint4*)cnt;
    unsigned sum = 0;
    #pragma unroll 4
    for (int i = 0; i < 16; ++i) {
        uint4 c = c4[t * 16 + i];
        sum += c.x + c.y + c.z + c.w;
    }
    lds[t] = sum;
    __syncthreads();
    for (int d = 1; d < 1024; d <<= 1) {
        unsigned v = (t >= d) ? lds[t - d] : 0u;
        __syncthreads();
        lds[t] += v;
        __syncthreads();
    }
    unsigned run = (t == 0) ? 0u : lds[t - 1];
    uint4* o4 = (uint4*)off;
    #pragma unroll 4
    for (int i = 0; i < 16; ++i) {
        uint4 c = c4[t * 16 + i];
        uint4 o;
        o.x = run;
        o.y = o.x + c.x;
        o.z = o.y + c.y;
        o.w = o.z + c.z;
        run = o.w + c.w;
        o4[t * 16 + i] = o;
    }
}

// ---------------- scatter: write fused {pid, yx} ----------------

__global__ __launch_bounds__(256) void scatter_kernel(
    const unsigned* __restrict__ yxp, unsigned* __restrict__ off,
    uint2* __restrict__ oy) {
    int pid = blockIdx.x * 256 + threadIdx.x;
    if (pid >= NPTS) return;
    unsigned p = yxp[pid];
    int y = (int)(p >> 16), x = (int)(p & 0xffffu);
    unsigned pos = atomicAdd(&off[bin_of(pid / NN, y, x)], 1u);
    uint2 q; q.x = (unsigned)pid; q.y = p;
    oy[pos] = q;
}

// ---------------- fused gather + MFMA MLP (XCD-swizzled, cached loads) ----

__global__ __launch_bounds__(512, 8) void mlp_fused(
    const float* __restrict__ pc0_map, const float* __restrict__ flow_map,
    const float* __restrict__ pc0_fea, const float* __restrict__ flows,
    const float* __restrict__ pose_flows, const float* __restrict__ radar_pose,
    const int* __restrict__ point_idxes,
    const uint2* __restrict__ oy,
    const float* __restrict__ wbuf,
    const float* __restrict__ b2, const float* __restrict__ W3,
    const float* __restrict__ b3,
    float* __restrict__ out)
{
    __shared__ uint4 Bf[832];
    __shared__ __align__(16) _Float16 zl[8][16 * 48];
    {
        const uint4* wsrc = (const uint4*)(wbuf + WB_BFRAG);
        for (int i = threadIdx.x; i < 832; i += 512) Bf[i] = wsrc[i];
    }
    __syncthreads();

    // bijective XCD-aware block swizzle (nwg = 6250, q = 781, r = 2):
    // blocks on one XCD get a contiguous chunk of the sorted tile order.
    int bid = blockIdx.x;
    int xcd = bid & 7;
    int idx = bid >> 3;
    const int q_ = NTILES / 8 / 8;          // 781
    const int r_ = (NTILES / 8) & 7;        // 2
    int swz = (xcd < r_ ? xcd * (q_ + 1) : r_ * (q_ + 1) + (xcd - r_) * q_) + idx;

    int wave = threadIdx.x >> 6;
    int l = threadIdx.x & 63;
    int lo = l & 15, hi = l >> 4;
    int tile = swz * 8 + wave;
    int s0 = tile * 16;

    uint2 q = oy[s0 + lo];
    int pid = (int)q.x;
    int y = (int)(q.y >> 16), x = (int)(q.y & 0xffffu);
    int b = pid / NN;

    const float* fm = flow_map + ((size_t)b * CC) * HWSZ + (size_t)y * WW + x;
    const float* pm = pc0_map  + ((size_t)b * CC) * HWSZ + (size_t)y * WW + x;

    // issue all scattered loads (cached: L2 dedups cross-tile line sharing)
    float v[32];
    #pragma unroll
    for (int t = 0; t < 4; ++t) {
        const float* mp = (t < 2) ? fm : pm;
        int ch0 = (t & 1) * 32 + hi * 8;
        #pragma unroll
        for (int j = 0; j < 8; ++j)
            v[t * 8 + j] = mp[(size_t)(ch0 + j) * HWSZ];
    }
    const f32x4* fe4 = (const f32x4*)(pc0_fea + (size_t)pid * 32 + hi * 8);
    f32x4 fa = fe4[0];
    f32x4 fb = fe4[1];
    float t0 = 0.f, t1 = 0.f, t2 = 0.f, t3 = 0.f, t4 = 0.f, t5 = 0.f;
    if (hi == 0) {
        const float* fl = flows + (size_t)pid * 3;
        t0 = fl[0]; t1 = fl[1]; t2 = fl[2];
        int pi = point_idxes[pid];
        const float* ps = (pi < PP) ? (pose_flows + ((size_t)b * PP + pi) * 3)
                                    : (radar_pose + ((size_t)b * RP + (pi - PP)) * 3);
        t3 = ps[0]; t4 = ps[1]; t5 = ps[2];
    }

    // build A fragments
    half8_t A[6];
    #pragma unroll
    for (int t = 0; t < 4; ++t) {
        #pragma unroll
        for (int j = 0; j < 8; ++j) A[t][j] = (_Float16)v[t * 8 + j];
    }
    A[4][0] = (_Float16)fa.x; A[4][1] = (_Float16)fa.y;
    A[4][2] = (_Float16)fa.z; A[4][3] = (_Float16)fa.w;
    A[4][4] = (_Float16)fb.x; A[4][5] = (_Float16)fb.y;
    A[4][6] = (_Float16)fb.z; A[4][7] = (_Float16)fb.w;
    {
        half8_t a5;
        #pragma unroll
        for (int j = 0; j < 8; ++j) a5[j] = (_Float16)0.f;
        if (hi == 0) {
            a5[0] = (_Float16)t0; a5[1] = (_Float16)t1; a5[2] = (_Float16)t2;
            a5[3] = (_Float16)t3; a5[4] = (_Float16)t4; a5[5] = (_Float16)t5;
            a5[6] = (_Float16)1.0f;
        }
        A[5] = a5;
    }

    // layer1 (collapsed): z[16 pts][32 ch]
    f32x4 acc0 = {0.f, 0.f, 0.f, 0.f};
    f32x4 acc1 = {0.f, 0.f, 0.f, 0.f};
    #pragma unroll
    for (int t = 0; t < 6; ++t) {
        half8_t B0, B1;
        uint4 u0 = Bf[t * 64 + l];
        uint4 u1 = Bf[(6 + t) * 64 + l];
        __builtin_memcpy(&B0, &u0, 16);
        __builtin_memcpy(&B1, &u1, 16);
        acc0 = __builtin_amdgcn_mfma_f32_16x16x32_f16(A[t], B0, acc0, 0, 0, 0);
        acc1 = __builtin_amdgcn_mfma_f32_16x16x32_f16(A[t], B1, acc1, 0, 0, 0);
    }

    // gelu -> z LDS (f16), C-layout: point = hi*4+r, ch = nt*16+lo
    _Float16* zw = zl[wave];
    #pragma unroll
    for (int r = 0; r < 4; ++r) {
        zw[(hi * 4 + r) * 48 + lo]      = (_Float16)gelu(acc0[r]);
        zw[(hi * 4 + r) * 48 + 16 + lo] = (_Float16)gelu(acc1[r]);
    }

    // layer2
    half8_t A2, B2;
    __builtin_memcpy(&A2, &zw[lo * 48 + hi * 8], 16);
    {
        uint4 u2 = Bf[768 + l];
        __builtin_memcpy(&B2, &u2, 16);
    }
    f32x4 zz4 = {0.f, 0.f, 0.f, 0.f};
    f32x4 acc2 = __builtin_amdgcn_mfma_f32_16x16x32_f16(A2, B2, zz4, 0, 0, 0);

    // epilogue
    float b2v = b2[lo];
    float w3v = W3[lo];
    float e0 = gelu(acc2[0] + b2v) * w3v;
    float e1 = gelu(acc2[1] + b2v) * w3v;
    float e2 = gelu(acc2[2] + b2v) * w3v;
    float e3 = gelu(acc2[3] + b2v) * w3v;
    #pragma unroll
    for (int m = 1; m <= 8; m <<= 1) {
        e0 += __shfl_xor(e0, m);
        e1 += __shfl_xor(e1, m);
        e2 += __shfl_xor(e2, m);
        e3 += __shfl_xor(e3, m);
    }
    int p2 = hi * 4 + lo;
    int pid2 = __shfl(pid, p2 & 15);
    if (lo < 4) {
        float zs = (lo == 0 ? e0 : lo == 1 ? e1 : lo == 2 ? e2 : e3) + b3[0];
        float score = 1.0f / (1.0f + expf(-zs));
        out[(size_t)NPTS + pid2] = score;
        out[pid2] = (score > 0.5f) ? 1.0f : 0.0f;
    }
}

extern "C" void kernel_launch(void* const* d_in, const int* in_sizes, int n_in,
                              void* d_out, int out_size, void* d_ws, size_t ws_size,
                              hipStream_t stream) {
    const float* pc0_map    = (const float*)d_in[0];
    const float* flow_map   = (const float*)d_in[1];
    const float* pc0_fea    = (const float*)d_in[2];
    const float* flows      = (const float*)d_in[3];
    const float* pose_flows = (const float*)d_in[4];
    const float* radar_pose = (const float*)d_in[5];
    const int*   voxel      = (const int*)d_in[6];
    const int*   pidx       = (const int*)d_in[7];
    const float* W_flow = (const float*)d_in[8];
    const float* b_flow = (const float*)d_in[9];
    const float* W_pc   = (const float*)d_in[10];
    const float* b_pc   = (const float*)d_in[11];
    const float* W1     = (const float*)d_in[12];
    const float* b1     = (const float*)d_in[13];
    const float* W2     = (const float*)d_in[14];
    const float* b2     = (const float*)d_in[15];
    const float* W3     = (const float*)d_in[16];
    const float* b3     = (const float*)d_in[17];

    // ws: cnt[NBINS] | off[NBINS] | oy[NPTS] (uint2) | yxp[NPTS] | wbuf
    size_t need = (size_t)(2 * NBINS + 3 * NPTS) * sizeof(unsigned)
                + (size_t)WBUF_WORDS * sizeof(float);
    if (ws_size < need) return;
    unsigned* cnt = (unsigned*)d_ws;
    unsigned* off = cnt + NBINS;
    uint2* oy = (uint2*)(off + NBINS);
    unsigned* yxp = (unsigned*)(oy + NPTS);
    float* wbuf = (float*)(yxp + NPTS);

    int ptBlocks = NPTS / 256;               // 3125 exact

    hipMemsetAsync(cnt, 0, (size_t)NBINS * sizeof(unsigned), stream);
    hipLaunchKernelGGL(hist_prep, dim3(ptBlocks), dim3(256), 0, stream,
                       voxel, cnt, yxp,
                       W_flow, b_flow, W_pc, b_pc, W1, b1, W2, wbuf);
    hipLaunchKernelGGL(scan_kernel, dim3(1), dim3(1024), 0, stream, cnt, off);
    hipLaunchKernelGGL(scatter_kernel, dim3(ptBlocks), dim3(256), 0, stream,
                       yxp, off, oy);
    hipLaunchKernelGGL(mlp_fused, dim3(NTILES / 8), dim3(512), 0, stream,
                       pc0_map, flow_map, pc0_fea, flows, pose_flows, radar_pose,
                       pidx, oy, wbuf, b2, W3, b3, (float*)d_out);
}

// Round 11
// 287.801 us; speedup vs baseline: 1.4142x; 1.1995x over previous
//
#include <hip/hip_runtime.h>

#define NB 4
#define NN 200000
#define HH 512
#define WW 512
#define CC 64
#define PP 150000
#define RP 100000
#define HWSZ (HH * WW)
#define NPTS (NB * NN)
#define NTILES (NPTS / 16)                 // 50000 (exact)
#define XSHIFT 4                           // 16 floats = one 64B line along x
#define BINS_PER_B (HH * (WW >> XSHIFT))   // 16384
#define NBINS (NB * BINS_PER_B)            // 65536

// wbuf layout (32-bit words):
#define WB_WCAT 0
#define WB_WTAIL 5120
#define WB_BCAT 5312
#define WB_BFRAG 5376
#define WB_BFRAG2 (WB_BFRAG + 3072)
#define WBUF_WORDS (WB_BFRAG2 + 256)       // 8704

#define ROWF 132                            // f16 per pts row (264B: 4B-ok, 8B-ok, bank ~1.6x)

typedef _Float16 half8_t __attribute__((ext_vector_type(8)));
typedef _Float16 half2_t __attribute__((ext_vector_type(2)));
typedef float f32x4 __attribute__((ext_vector_type(4)));

__device__ __forceinline__ unsigned packh(float a, float b) {
    half2_t h; h.x = (_Float16)a; h.y = (_Float16)b;
    unsigned u; __builtin_memcpy(&u, &h, 4); return u;
}
__device__ __forceinline__ float gelu(float v) {
    return 0.5f * v * (1.0f + erff(v * 0.70710678118654752f));
}
__device__ __forceinline__ int bin_of(int b, int y, int x) {
    return b * BINS_PER_B + y * (WW >> XSHIFT) + (x >> XSHIFT);
}

// ---------------- prep1: zero bins + collapsed weights (grid 64) ----------------

__global__ __launch_bounds__(256) void prep1(
    const float* __restrict__ Wf, const float* __restrict__ bf,
    const float* __restrict__ Wp, const float* __restrict__ bp,
    const float* __restrict__ W1, const float* __restrict__ b1,
    float* __restrict__ wbuf, unsigned* __restrict__ cnt)
{
    int g = blockIdx.x * 256 + threadIdx.x;      // 0..16383
    uint4 z4 = {0u, 0u, 0u, 0u};
    ((uint4*)cnt)[g] = z4;                        // 16384*4 = 65536 bins

    if (g < 5120) {                               // Wcat
        int r = g >> 5, j = g & 31;
        float s = 0.f;
        if (r < 64) {
            for (int k = 0; k < 32; ++k) s += Wf[r * 32 + k] * W1[k * 32 + j];
        } else {
            int rr = r - 64;
            for (int k = 0; k < 32; ++k) s += Wp[rr * 32 + k] * W1[(32 + k) * 32 + j];
        }
        wbuf[WB_WCAT + g] = s;
    } else if (g < 5312) {                        // Wtail
        int idx = g - 5120;
        int r = idx >> 5, j = idx & 31;
        float s = 0.f;
        for (int k = 0; k < 32; ++k) s += Wf[(64 + r) * 32 + k] * W1[k * 32 + j];
        wbuf[WB_WTAIL + idx] = s;
    } else if (g < 5344) {                        // bcat
        int j = g - 5312;
        float s = b1[j];
        for (int k = 0; k < 32; ++k)
            s += bf[k] * W1[k * 32 + j] + bp[k] * W1[(32 + k) * 32 + j];
        wbuf[WB_BCAT + j] = s;
    }
}

// ---------------- hist (+ yx cache) ----------------

__global__ __launch_bounds__(256) void hist_kernel(
    const int* __restrict__ voxel, unsigned* __restrict__ cnt,
    unsigned* __restrict__ yxp) {
    int pid = blockIdx.x * 256 + threadIdx.x;
    if (pid >= NPTS) return;
    int b = pid / NN;
    int y = voxel[(size_t)pid * 3 + 1];
    int x = voxel[(size_t)pid * 3 + 2];
    yxp[pid] = ((unsigned)y << 16) | (unsigned)x;
    atomicAdd(&cnt[bin_of(b, y, x)], 1u);
}

// ---------------- scan (single block) + BF fragment build tail ----------------

__device__ __forceinline__ float wrowf(const float* __restrict__ wbuf, int k, int col) {
    if (k < 160) return wbuf[WB_WCAT + k * 32 + col];
    if (k < 166) return wbuf[WB_WTAIL + (k - 160) * 32 + col];
    if (k == 166) return wbuf[WB_BCAT + col];
    return 0.f;
}

__global__ __launch_bounds__(1024) void scan_kernel(
    const unsigned* __restrict__ cnt, unsigned* __restrict__ off,
    const float* __restrict__ wbufc, float* __restrict__ wbuf,
    const float* __restrict__ W2) {
    __shared__ unsigned lds[1024];
    int t = threadIdx.x;
    const uint4* c4 = (const uint4*)cnt;
    unsigned sum = 0;
    #pragma unroll 4
    for (int i = 0; i < 16; ++i) {
        uint4 c = c4[t * 16 + i];
        sum += c.x + c.y + c.z + c.w;
    }
    lds[t] = sum;
    __syncthreads();
    for (int d = 1; d < 1024; d <<= 1) {
        unsigned v = (t >= d) ? lds[t - d] : 0u;
        __syncthreads();
        lds[t] += v;
        __syncthreads();
    }
    unsigned run = (t == 0) ? 0u : lds[t - 1];
    uint4* o4 = (uint4*)off;
    #pragma unroll 4
    for (int i = 0; i < 16; ++i) {
        uint4 c = c4[t * 16 + i];
        uint4 o;
        o.x = run;
        o.y = o.x + c.x;
        o.z = o.y + c.y;
        o.w = o.z + c.z;
        run = o.w + c.w;
        o4[t * 16 + i] = o;
    }
    // BF fragment build (independent of scan data; wbufc written by prep1)
    unsigned* BF = (unsigned*)(wbuf + WB_BFRAG);
    for (int idx = t; idx < 3072 + 256; idx += 1024) {
        if (idx < 3072) {
            int w = idx & 3;
            int slot = idx >> 2;
            int l = slot & 63;
            int rest = slot >> 6;
            int tt = rest % 6, nt = rest / 6;
            int k = tt * 32 + (l >> 4) * 8 + w * 2;
            int col = nt * 16 + (l & 15);
            BF[idx] = packh(wrowf(wbufc, k, col), wrowf(wbufc, k + 1, col));
        } else {
            int i2 = idx - 3072;
            int w = i2 & 3, l = i2 >> 2;
            int k2 = (l >> 4) * 8 + w * 2, col = l & 15;
            BF[i2 + 3072] = packh(W2[k2 * 16 + col], W2[(k2 + 1) * 16 + col]);
        }
    }
}

// ---------------- scatter: write fused {pid, yx} ----------------

__global__ __launch_bounds__(256) void scatter_kernel(
    const unsigned* __restrict__ yxp, unsigned* __restrict__ off,
    uint2* __restrict__ oy) {
    int pid = blockIdx.x * 256 + threadIdx.x;
    if (pid >= NPTS) return;
    unsigned p = yxp[pid];
    int y = (int)(p >> 16), x = (int)(p & 0xffffu);
    unsigned pos = atomicAdd(&off[bin_of(pid / NN, y, x)], 1u);
    uint2 q; q.x = (unsigned)pid; q.y = p;
    oy[pos] = q;
}

// ---------------- fused: plane-streaming LDS gather + MFMA MLP ----------------
// Block = 512 thr = 8 waves = 128 sorted points. Load phase: wave w streams
// channel-group (w>>1) for 64 consecutive points (one plane per instruction,
// gather_pack's access shape) into pts[][]. Compute: wave w owns tile w.

__global__ __launch_bounds__(512, 4) void mlp_fused(
    const float* __restrict__ pc0_map, const float* __restrict__ flow_map,
    const float* __restrict__ pc0_fea, const float* __restrict__ flows,
    const float* __restrict__ pose_flows, const float* __restrict__ radar_pose,
    const int* __restrict__ point_idxes,
    const uint2* __restrict__ oy,
    const float* __restrict__ wbuf,
    const float* __restrict__ b2, const float* __restrict__ W3,
    const float* __restrict__ b3,
    float* __restrict__ out)
{
    __shared__ uint4 Bf[832];                               // 13312 B
    __shared__ __align__(16) _Float16 pts[128][ROWF];       // 33792 B; zl aliases
    _Float16* zlbase = &pts[0][0];

    {
        const uint4* wsrc = (const uint4*)(wbuf + WB_BFRAG);
        for (int i = threadIdx.x; i < 832; i += 512) Bf[i] = wsrc[i];
    }

    // bijective XCD-aware block swizzle (nwg = 6250 = 8*781 + 2)
    int bid = blockIdx.x;
    int xcd = bid & 7;
    int idx = bid >> 3;
    const int q_ = 781, r_ = 2;
    int swz = (xcd < r_ ? xcd * (q_ + 1) : r_ * (q_ + 1) + (xcd - r_) * q_) + idx;
    int s0b = swz * 128;                    // block's first sorted slot

    int tid = threadIdx.x;
    int lane = tid & 63, w = tid >> 6;

    // ---- load phase: 1 plane per wave-instruction, 64 consecutive points ----
    {
        int ptl = (w & 1) * 64 + lane;      // 0..127
        uint2 qp = oy[s0b + ptl];
        int pidp = (int)qp.x;
        int yp = (int)(qp.y >> 16), xp = (int)(qp.y & 0xffffu);
        int bp = pidp / NN;
        int cg = w >> 1;                    // 0..3 -> pts ch base cg*32
        const float* mbase = (cg < 2 ? flow_map : pc0_map)
            + ((size_t)(bp * CC + (cg & 1) * 32)) * HWSZ + (size_t)yp * WW + xp;
        #pragma unroll
        for (int c = 0; c < 32; c += 8) {
            float u[8];
            #pragma unroll
            for (int j = 0; j < 8; ++j) u[j] = mbase[(size_t)(c + j) * HWSZ];
            #pragma unroll
            for (int j = 0; j < 8; j += 2) {
                unsigned pk = packh(u[j], u[j + 1]);
                *(unsigned*)&pts[ptl][cg * 32 + c + j] = pk;
            }
        }
    }
    __syncthreads();

    // ---- compute phase: wave w owns tile w (points w*16 .. +15) ----
    int lo = lane & 15, hi = lane >> 4;
    int sp = w * 16 + lo;
    uint2 q = oy[s0b + sp];
    int pid = (int)q.x;
    int b = pid / NN;

    half8_t A[6];
    #pragma unroll
    for (int t = 0; t < 4; ++t) {
        int ch0 = (t < 2 ? 0 : 64) + (t & 1) * 32 + hi * 8;
        __builtin_memcpy(&A[t], &pts[sp][ch0], 16);   // 8B-aligned -> 2x ds_read_b64
    }
    {
        const f32x4* fe4 = (const f32x4*)(pc0_fea + (size_t)pid * 32 + hi * 8);
        f32x4 fa = fe4[0];
        f32x4 fb = fe4[1];
        A[4][0] = (_Float16)fa.x; A[4][1] = (_Float16)fa.y;
        A[4][2] = (_Float16)fa.z; A[4][3] = (_Float16)fa.w;
        A[4][4] = (_Float16)fb.x; A[4][5] = (_Float16)fb.y;
        A[4][6] = (_Float16)fb.z; A[4][7] = (_Float16)fb.w;
    }
    {
        half8_t a5;
        #pragma unroll
        for (int j = 0; j < 8; ++j) a5[j] = (_Float16)0.f;
        if (hi == 0) {
            const float* fl = flows + (size_t)pid * 3;
            int pi = point_idxes[pid];
            const float* ps = (pi < PP) ? (pose_flows + ((size_t)b * PP + pi) * 3)
                                        : (radar_pose + ((size_t)b * RP + (pi - PP)) * 3);
            a5[0] = (_Float16)fl[0]; a5[1] = (_Float16)fl[1]; a5[2] = (_Float16)fl[2];
            a5[3] = (_Float16)ps[0]; a5[4] = (_Float16)ps[1]; a5[5] = (_Float16)ps[2];
            a5[6] = (_Float16)1.0f;
        }
        A[5] = a5;
    }

    // layer1 (collapsed): z[16 pts][32 ch]
    f32x4 acc0 = {0.f, 0.f, 0.f, 0.f};
    f32x4 acc1 = {0.f, 0.f, 0.f, 0.f};
    #pragma unroll
    for (int t = 0; t < 6; ++t) {
        half8_t B0, B1;
        uint4 u0 = Bf[t * 64 + lane];
        uint4 u1 = Bf[(6 + t) * 64 + lane];
        __builtin_memcpy(&B0, &u0, 16);
        __builtin_memcpy(&B1, &u1, 16);
        acc0 = __builtin_amdgcn_mfma_f32_16x16x32_f16(A[t], B0, acc0, 0, 0, 0);
        acc1 = __builtin_amdgcn_mfma_f32_16x16x32_f16(A[t], B1, acc1, 0, 0, 0);
    }

    // zl aliases pts: all waves must be done reading pts first
    __syncthreads();

    _Float16* zw = zlbase + w * (16 * 48);
    #pragma unroll
    for (int r = 0; r < 4; ++r) {
        zw[(hi * 4 + r) * 48 + lo]      = (_Float16)gelu(acc0[r]);
        zw[(hi * 4 + r) * 48 + 16 + lo] = (_Float16)gelu(acc1[r]);
    }

    // layer2
    half8_t A2, B2;
    __builtin_memcpy(&A2, &zw[lo * 48 + hi * 8], 16);
    {
        uint4 u2 = Bf[768 + lane];
        __builtin_memcpy(&B2, &u2, 16);
    }
    f32x4 zz4 = {0.f, 0.f, 0.f, 0.f};
    f32x4 acc2 = __builtin_amdgcn_mfma_f32_16x16x32_f16(A2, B2, zz4, 0, 0, 0);

    // epilogue
    float b2v = b2[lo];
    float w3v = W3[lo];
    float e0 = gelu(acc2[0] + b2v) * w3v;
    float e1 = gelu(acc2[1] + b2v) * w3v;
    float e2 = gelu(acc2[2] + b2v) * w3v;
    float e3 = gelu(acc2[3] + b2v) * w3v;
    #pragma unroll
    for (int m = 1; m <= 8; m <<= 1) {
        e0 += __shfl_xor(e0, m);
        e1 += __shfl_xor(e1, m);
        e2 += __shfl_xor(e2, m);
        e3 += __shfl_xor(e3, m);
    }
    int p2 = hi * 4 + lo;
    int pid2 = __shfl(pid, p2 & 15);
    if (lo < 4) {
        float zs = (lo == 0 ? e0 : lo == 1 ? e1 : lo == 2 ? e2 : e3) + b3[0];
        float score = 1.0f / (1.0f + expf(-zs));
        out[(size_t)NPTS + pid2] = score;
        out[pid2] = (score > 0.5f) ? 1.0f : 0.0f;
    }
}

extern "C" void kernel_launch(void* const* d_in, const int* in_sizes, int n_in,
                              void* d_out, int out_size, void* d_ws, size_t ws_size,
                              hipStream_t stream) {
    const float* pc0_map    = (const float*)d_in[0];
    const float* flow_map   = (const float*)d_in[1];
    const float* pc0_fea    = (const float*)d_in[2];
    const float* flows      = (const float*)d_in[3];
    const float* pose_flows = (const float*)d_in[4];
    const float* radar_pose = (const float*)d_in[5];
    const int*   voxel      = (const int*)d_in[6];
    const int*   pidx       = (const int*)d_in[7];
    const float* W_flow = (const float*)d_in[8];
    const float* b_flow = (const float*)d_in[9];
    const float* W_pc   = (const float*)d_in[10];
    const float* b_pc   = (const float*)d_in[11];
    const float* W1     = (const float*)d_in[12];
    const float* b1     = (const float*)d_in[13];
    const float* W2     = (const float*)d_in[14];
    const float* b2     = (const float*)d_in[15];
    const float* W3     = (const float*)d_in[16];
    const float* b3     = (const float*)d_in[17];

    // ws: cnt[NBINS] | off[NBINS] | oy[NPTS] (uint2) | yxp[NPTS] | wbuf
    size_t need = (size_t)(2 * NBINS + 3 * NPTS) * sizeof(unsigned)
                + (size_t)WBUF_WORDS * sizeof(float);
    if (ws_size < need) return;
    unsigned* cnt = (unsigned*)d_ws;
    unsigned* off = cnt + NBINS;
    uint2* oy = (uint2*)(off + NBINS);
    unsigned* yxp = (unsigned*)(oy + NPTS);
    float* wbuf = (float*)(yxp + NPTS);

    int ptBlocks = NPTS / 256;               // 3125 exact

    hipLaunchKernelGGL(prep1, dim3(64), dim3(256), 0, stream,
                       W_flow, b_flow, W_pc, b_pc, W1, b1, wbuf, cnt);
    hipLaunchKernelGGL(hist_kernel, dim3(ptBlocks), dim3(256), 0, stream,
                       voxel, cnt, yxp);
    hipLaunchKernelGGL(scan_kernel, dim3(1), dim3(1024), 0, stream,
                       cnt, off, wbuf, wbuf, W2);
    hipLaunchKernelGGL(scatter_kernel, dim3(ptBlocks), dim3(256), 0, stream,
                       yxp, off, oy);
    hipLaunchKernelGGL(mlp_fused, dim3(NTILES / 8), dim3(512), 0, stream,
                       pc0_map, flow_map, pc0_fea, flows, pose_flows, radar_pose,
                       pidx, oy, wbuf, b2, W3, b3, (float*)d_out);
}